// Round 6
// baseline (2962.499 us; speedup 1.0000x reference)
//
#include <hip/hip_runtime.h>
#include <math.h>

// SLAYER MLP forward: spike(psp(W2 @ spike(psp(W1 @ x))))
// B=256, IN=78, HID=16, OUT=20, T=1000, K=100 (SRM alpha, tau=10)
//
// fp64 accumulation everywhere (absmax 0.0 rounds 0-5), fp32 rounding at
// reference materialization points (einsum outputs z1/z2, final u).
//
// Round-6: fir_g only. (a) z staged in LDS as fp32 (same values, converted
// to double at register load) -> conflict-free float4 reads + half the LDS;
// (b) __launch_bounds__(256,4) caps VGPR at 128 (was 256, occupancy 8.6%).

#define B_     256
#define IN_    78
#define HID_   16
#define OUT_   20
#define T_     1000
#define TT_    125
#define J_     224              // TT + K - 1
#define ZSTR_  228              // fp32 LDS row stride (224 + 4; stride%4==0)

// ---------------- FIR building blocks (named scalars only) ----------------
// Window W[0..10] = quads (A,B,C). Group with eps[s0..s0+3]:
//   u[d] += eps[s0+e] * W[d-e+3]
#define GRP(EP, A0,A1,A2,A3, B0,B1,B2,B3, C0,C1,C2) { \
  const double2 e01_ = *(const double2*)(EP); \
  const double2 e23_ = *(const double2*)((EP)+2); \
  u0 += e01_.x*(A3); u1 += e01_.x*(B0); u2 += e01_.x*(B1); u3 += e01_.x*(B2); \
  u4 += e01_.x*(B3); u5 += e01_.x*(C0); u6 += e01_.x*(C1); u7 += e01_.x*(C2); \
  u0 += e01_.y*(A2); u1 += e01_.y*(A3); u2 += e01_.y*(B0); u3 += e01_.y*(B1); \
  u4 += e01_.y*(B2); u5 += e01_.y*(B3); u6 += e01_.y*(C0); u7 += e01_.y*(C1); \
  u0 += e23_.x*(A1); u1 += e23_.x*(A2); u2 += e23_.x*(A3); u3 += e23_.x*(B0); \
  u4 += e23_.x*(B1); u5 += e23_.x*(B2); u6 += e23_.x*(B3); u7 += e23_.x*(C0); \
  u0 += e23_.y*(A0); u1 += e23_.y*(A1); u2 += e23_.y*(A2); u3 += e23_.y*(A3); \
  u4 += e23_.y*(B0); u5 += e23_.y*(B1); u6 += e23_.y*(B2); u7 += e23_.y*(B3); }

#define LOADD(X0,X1,X2,X3, P) { \
  const double2 la_ = *(const double2*)(P); \
  const double2 lb_ = *(const double2*)((P)+2); \
  X0 = la_.x; X1 = la_.y; X2 = lb_.x; X3 = lb_.y; }

#define LOADF(X0,X1,X2,X3, P) { \
  const float4 lf_ = *(const float4*)(P); \
  X0 = (double)lf_.x; X1 = (double)lf_.y; X2 = (double)lf_.z; X3 = (double)lf_.w; }

// fp32-window step: load quad w = 24-G (float offset 4*(24-G) in zrow), GRP.
// Requires in scope: zrow (const float*, includes 8*q), eps_d, u0..u7.
#define STEPF(G, N0,N1,N2,N3, P0,P1,P2,P3, Q0,Q1,Q2) \
  LOADF(N0,N1,N2,N3, zrow + 4*(24-(G))); \
  GRP(eps_d + 4*(G), N0,N1,N2,N3, P0,P1,P2,P3, Q0,Q1,Q2)

#define FIR24_F \
  STEPF( 1, C0,C1,C2,C3, A0,A1,A2,A3, B0,B1,B2) \
  STEPF( 2, B0,B1,B2,B3, C0,C1,C2,C3, A0,A1,A2) \
  STEPF( 3, A0,A1,A2,A3, B0,B1,B2,B3, C0,C1,C2) \
  STEPF( 4, C0,C1,C2,C3, A0,A1,A2,A3, B0,B1,B2) \
  STEPF( 5, B0,B1,B2,B3, C0,C1,C2,C3, A0,A1,A2) \
  STEPF( 6, A0,A1,A2,A3, B0,B1,B2,B3, C0,C1,C2) \
  STEPF( 7, C0,C1,C2,C3, A0,A1,A2,A3, B0,B1,B2) \
  STEPF( 8, B0,B1,B2,B3, C0,C1,C2,C3, A0,A1,A2) \
  STEPF( 9, A0,A1,A2,A3, B0,B1,B2,B3, C0,C1,C2) \
  STEPF(10, C0,C1,C2,C3, A0,A1,A2,A3, B0,B1,B2) \
  STEPF(11, B0,B1,B2,B3, C0,C1,C2,C3, A0,A1,A2) \
  STEPF(12, A0,A1,A2,A3, B0,B1,B2,B3, C0,C1,C2) \
  STEPF(13, C0,C1,C2,C3, A0,A1,A2,A3, B0,B1,B2) \
  STEPF(14, B0,B1,B2,B3, C0,C1,C2,C3, A0,A1,A2) \
  STEPF(15, A0,A1,A2,A3, B0,B1,B2,B3, C0,C1,C2) \
  STEPF(16, C0,C1,C2,C3, A0,A1,A2,A3, B0,B1,B2) \
  STEPF(17, B0,B1,B2,B3, C0,C1,C2,C3, A0,A1,A2) \
  STEPF(18, A0,A1,A2,A3, B0,B1,B2,B3, C0,C1,C2) \
  STEPF(19, C0,C1,C2,C3, A0,A1,A2,A3, B0,B1,B2) \
  STEPF(20, B0,B1,B2,B3, C0,C1,C2,C3, A0,A1,A2) \
  STEPF(21, A0,A1,A2,A3, B0,B1,B2,B3, C0,C1,C2) \
  STEPF(22, C0,C1,C2,C3, A0,A1,A2,A3, B0,B1,B2) \
  STEPF(23, B0,B1,B2,B3, C0,C1,C2,C3, A0,A1,A2) \
  STEPF(24, A0,A1,A2,A3, B0,B1,B2,B3, C0,C1,C2)

__device__ __forceinline__ void init_eps_d(double* eps_d, int tid) {
  if (tid < 100) {
    float a = (float)tid / 10.0f;           // identical fp32 ops to reference
    float e = a * expf(1.0f - a);
    eps_d[tid] = (double)e;                 // exact widening
  }
}

// -------- mm1: z1[b,h,t] = sum_i W1[h,i] * x[b,i,t]  (proven clean) --------
// grid = 256 b * 4 t-chunks of 256; block 256 = 8 h-pairs x 32 t-octets
__global__ __launch_bounds__(256) void mm1(
    const float* __restrict__ x, const float* __restrict__ W1,
    float* __restrict__ z1)
{
  __shared__ double xe[13 * 128];
  __shared__ double xo[13 * 128];
  __shared__ double wd[16 * 80];

  const int tid = threadIdx.x;
  const int b   = blockIdx.x >> 2;
  const int tc  = blockIdx.x & 3;
  const int tcb = tc * 256;

  for (int idx = tid; idx < HID_ * IN_; idx += 256)
    wd[(idx / IN_) * 80 + (idx % IN_)] = (double)W1[idx];

  const int c    = tid;
  const int slot = ((c >> 3) << 2) | (c & 3);
  double* dst = (((c >> 2) & 1) ? xo : xe) + slot;
  const int t_c  = tcb + c;
  const bool cok = (t_c < T_);

  const int p = tid >> 5;
  const int q = tid & 31;

  double m00=0,m01=0,m02=0,m03=0,m04=0,m05=0,m06=0,m07=0;
  double m10=0,m11=0,m12=0,m13=0,m14=0,m15=0,m16=0,m17=0;

  for (int ci = 0; ci < 6; ++ci) {
    __syncthreads();
    {
      const float* xp = x + ((size_t)b * IN_ + ci * 13) * T_ + t_c;
#pragma unroll
      for (int r = 0; r < 13; ++r)
        dst[r * 128] = cok ? (double)xp[r * T_] : 0.0;
    }
    __syncthreads();
#pragma unroll
    for (int i = 0; i < 13; ++i) {
      double d0,d1,d2,d3,d4,d5,d6,d7;
      LOADD(d0,d1,d2,d3, &xe[i * 128 + 4 * q]);
      LOADD(d4,d5,d6,d7, &xo[i * 128 + 4 * q]);
      const double w0 = wd[(2*p)     * 80 + ci * 13 + i];
      const double w1 = wd[(2*p + 1) * 80 + ci * 13 + i];
      m00 += w0*d0; m01 += w0*d1; m02 += w0*d2; m03 += w0*d3;
      m04 += w0*d4; m05 += w0*d5; m06 += w0*d6; m07 += w0*d7;
      m10 += w1*d0; m11 += w1*d1; m12 += w1*d2; m13 += w1*d3;
      m14 += w1*d4; m15 += w1*d5; m16 += w1*d6; m17 += w1*d7;
    }
  }

  const int t8 = tcb + 8 * q;
  if (t8 + 7 < T_) {
    float* o0 = &z1[((size_t)b * HID_ + 2*p) * T_ + t8];
    float* o1 = &z1[((size_t)b * HID_ + 2*p + 1) * T_ + t8];
    *(float4*)(o0)     = make_float4((float)m00,(float)m01,(float)m02,(float)m03);
    *(float4*)(o0 + 4) = make_float4((float)m04,(float)m05,(float)m06,(float)m07);
    *(float4*)(o1)     = make_float4((float)m10,(float)m11,(float)m12,(float)m13);
    *(float4*)(o1 + 4) = make_float4((float)m14,(float)m15,(float)m16,(float)m17);
  }
}

// -------- mm2: z2[b,o,t] = sum_h W2[o,h] * s1[b,h,t] -----------------------
__global__ __launch_bounds__(256) void mm2(
    const float* __restrict__ s1, const float* __restrict__ W2,
    float* __restrict__ z2)
{
  __shared__ double se[16 * 128];
  __shared__ double so[16 * 128];
  __shared__ double wd[OUT_ * HID_];

  const int tid = threadIdx.x;
  const int b   = blockIdx.x >> 2;
  const int tc  = blockIdx.x & 3;
  const int tcb = tc * 256;

  for (int idx = tid; idx < OUT_ * HID_; idx += 256)   // 320 > 256: strided
    wd[idx] = (double)W2[idx];

  const int c    = tid;
  const int slot = ((c >> 3) << 2) | (c & 3);
  double* dst = (((c >> 2) & 1) ? so : se) + slot;
  const int t_c  = tcb + c;
  const bool cok = (t_c < T_);
  {
    const float* sp = s1 + (size_t)b * HID_ * T_ + t_c;
#pragma unroll
    for (int r = 0; r < HID_; ++r)
      dst[r * 128] = cok ? (double)sp[r * T_] : 0.0;
  }
  __syncthreads();

  const int p  = tid >> 5;
  const int q  = tid & 31;
  const int t8 = tcb + 8 * q;

  for (int pg = p; pg < 10; pg += 8) {
    double m00=0,m01=0,m02=0,m03=0,m04=0,m05=0,m06=0,m07=0;
    double m10=0,m11=0,m12=0,m13=0,m14=0,m15=0,m16=0,m17=0;
#pragma unroll
    for (int i = 0; i < HID_; ++i) {
      double d0,d1,d2,d3,d4,d5,d6,d7;
      LOADD(d0,d1,d2,d3, &se[i * 128 + 4 * q]);
      LOADD(d4,d5,d6,d7, &so[i * 128 + 4 * q]);
      const double w0 = wd[(2*pg)     * HID_ + i];
      const double w1 = wd[(2*pg + 1) * HID_ + i];
      m00 += w0*d0; m01 += w0*d1; m02 += w0*d2; m03 += w0*d3;
      m04 += w0*d4; m05 += w0*d5; m06 += w0*d6; m07 += w0*d7;
      m10 += w1*d0; m11 += w1*d1; m12 += w1*d2; m13 += w1*d3;
      m14 += w1*d4; m15 += w1*d5; m16 += w1*d6; m17 += w1*d7;
    }
    if (t8 + 7 < T_) {
      float* o0 = &z2[((size_t)b * OUT_ + 2*pg) * T_ + t8];
      float* o1 = &z2[((size_t)b * OUT_ + 2*pg + 1) * T_ + t8];
      *(float4*)(o0)     = make_float4((float)m00,(float)m01,(float)m02,(float)m03);
      *(float4*)(o0 + 4) = make_float4((float)m04,(float)m05,(float)m06,(float)m07);
      *(float4*)(o1)     = make_float4((float)m10,(float)m11,(float)m12,(float)m13);
      *(float4*)(o1 + 4) = make_float4((float)m14,(float)m15,(float)m16,(float)m17);
    }
  }
}

// -------- fir_g: sout = spike(FIR(zin)), R rows (16 or 20) -----------------
// z staged in LDS as fp32 (bit-identical: converted to double at reg load).
// tile_fixed < 0: grid = B*8; else grid = B, single tile (in-place safe when
// tiles launched in DESCENDING order; tile k reads t < 125(k+1)).
__global__ __launch_bounds__(256, 4) void fir_g(
    const float* __restrict__ zin, float* __restrict__ sout,
    int R, int tile_fixed)
{
  __shared__ float zf[OUT_ * ZSTR_];   // 18,240 B (R<=20)
  __shared__ __align__(16) double eps_d[100];

  const int tid  = threadIdx.x;
  const int b    = (tile_fixed >= 0) ? (int)blockIdx.x : (int)(blockIdx.x >> 3);
  const int tile = (tile_fixed >= 0) ? tile_fixed      : (int)(blockIdx.x & 7);
  const int t0   = tile * TT_;

  init_eps_d(eps_d, tid);
  for (int idx = tid; idx < R * ZSTR_; idx += 256) {
    const int cc = idx % ZSTR_;                 // row-major: idx = r*ZSTR_+cc
    const int t  = t0 - 99 + cc;
    const int r  = idx / ZSTR_;
    zf[idx] = (cc < J_ && t >= 0 && t < T_)
                ? zin[((size_t)b * R + r) * T_ + t] : 0.0f;
  }
  __syncthreads();

  for (int task = tid; task < R * 16; task += 256) {
    const int h = task >> 4, q = task & 15;
    const float* zrow = &zf[h * ZSTR_ + 8 * q];  // window cols rel. 0..106
    double u0=0,u1=0,u2=0,u3=0,u4=0,u5=0,u6=0,u7=0;
    double A0,A1,A2,A3,B0,B1,B2,B3,C0,C1,C2,C3;
    LOADF(A0,A1,A2,A3, zrow + 96);               // quad 24
    LOADF(B0,B1,B2,B3, zrow + 100);              // quad 25
    LOADF(C0,C1,C2,C3, zrow + 104);              // quad 26
    GRP(eps_d, A0,A1,A2,A3, B0,B1,B2,B3, C0,C1,C2)
    FIR24_F

    const size_t base = ((size_t)b * R + h) * T_ + t0 + 8 * q;
    const int tb = 8 * q;
    const float f0=(float)u0, f1=(float)u1, f2=(float)u2, f3=(float)u3;
    const float f4=(float)u4, f5=(float)u5, f6=(float)u6, f7=(float)u7;
    sout[base + 0] = (f0 >= 1.0f) ? 1.0f : 0.0f;   // tb+3 <= 123 always valid
    sout[base + 1] = (f1 >= 1.0f) ? 1.0f : 0.0f;
    sout[base + 2] = (f2 >= 1.0f) ? 1.0f : 0.0f;
    sout[base + 3] = (f3 >= 1.0f) ? 1.0f : 0.0f;
    if (tb + 4 < TT_) sout[base + 4] = (f4 >= 1.0f) ? 1.0f : 0.0f;
    if (tb + 5 < TT_) sout[base + 5] = (f5 >= 1.0f) ? 1.0f : 0.0f;
    if (tb + 6 < TT_) sout[base + 6] = (f6 >= 1.0f) ? 1.0f : 0.0f;
    if (tb + 7 < TT_) sout[base + 7] = (f7 >= 1.0f) ? 1.0f : 0.0f;
  }
}

extern "C" void kernel_launch(void* const* d_in, const int* in_sizes, int n_in,
                              void* d_out, int out_size, void* d_ws, size_t ws_size,
                              hipStream_t stream) {
  const float* x  = (const float*)d_in[0];
  const float* W1 = (const float*)d_in[1];
  const float* W2 = (const float*)d_in[2];
  float* outp = (float*)d_out;
  float* base = (float*)d_ws;

  const size_t Z1E = (size_t)B_ * HID_ * T_;   // 4.096M floats (16.4 MB)
  const size_t Z2E = (size_t)B_ * OUT_ * T_;   // 5.120M floats (20.5 MB)

  if (ws_size >= (Z1E + Z2E) * sizeof(float)) {
    float* z1 = base;
    float* s1 = base + Z2E;
    float* z2 = base;                            // reuses z1 space
    mm1<<<dim3(B_ * 4), dim3(256), 0, stream>>>(x, W1, z1);
    fir_g<<<dim3(B_ * 8), dim3(256), 0, stream>>>(z1, s1, HID_, -1);
    mm2<<<dim3(B_ * 4), dim3(256), 0, stream>>>(s1, W2, z2);
    fir_g<<<dim3(B_ * 8), dim3(256), 0, stream>>>(z2, outp, OUT_, -1);
  } else if (ws_size >= 2 * Z1E * sizeof(float)) {
    float* z1 = base;
    float* s1 = base + Z1E;
    mm1<<<dim3(B_ * 4), dim3(256), 0, stream>>>(x, W1, z1);
    fir_g<<<dim3(B_ * 8), dim3(256), 0, stream>>>(z1, s1, HID_, -1);
    mm2<<<dim3(B_ * 4), dim3(256), 0, stream>>>(s1, W2, outp);
    for (int k = 7; k >= 0; --k)
      fir_g<<<dim3(B_), dim3(256), 0, stream>>>(outp, outp, OUT_, k);
  } else {
    float* z1 = base;
    mm1<<<dim3(B_ * 4), dim3(256), 0, stream>>>(x, W1, z1);
    for (int k = 7; k >= 0; --k)
      fir_g<<<dim3(B_), dim3(256), 0, stream>>>(z1, z1, HID_, k);
    mm2<<<dim3(B_ * 4), dim3(256), 0, stream>>>(z1, W2, outp);
    for (int k = 7; k >= 0; --k)
      fir_g<<<dim3(B_), dim3(256), 0, stream>>>(outp, outp, OUT_, k);
  }
}

// Round 7
// 135.206 us; speedup vs baseline: 21.9111x; 21.9111x over previous
//
#include <hip/hip_runtime.h>
#include <math.h>

// SLAYER MLP forward: spike(psp(W2 @ spike(psp(W1 @ x))))
// B=256, IN=78, HID=16, OUT=20, T=1000, K=100 (SRM alpha, tau=10)
//
// fp64 accumulation everywhere (absmax 0.0 rounds 0-6), fp32 rounding at
// reference materialization points (einsum outputs z1/z2, final u).
//
// Round-7: fir_g FIR is now a ROLLED period-3 loop (8 iters x 3 groups) with
// named-scalar register rotation. Round 5's full unroll ballooned to 256 VGPR
// (scheduler hoisted all 27 ds_reads); round 6's (256,4) cap turned that into
// spills (VGPR=64, 4.3 GB scratch traffic, 1630us). Rolled loop bounds
// liveness structurally (~70 VGPR live). fp32 LDS staging kept (conflict-free,
// verified bit-identical). No launch-bounds cap.

#define B_     256
#define IN_    78
#define HID_   16
#define OUT_   20
#define T_     1000
#define TT_    125
#define J_     224              // TT + K - 1
#define ZSTR_  228              // fp32 LDS row stride (224 + 4 pad)

// ---------------- building blocks (named scalars only) ----------------
// Window W[0..10] over z; group with eps[s0..s0+3]: u[d] += eps[s0+e]*W[d-e+3]
#define GRP(EP, A0,A1,A2,A3, B0,B1,B2,B3, C0,C1,C2) { \
  const double2 e01_ = *(const double2*)(EP); \
  const double2 e23_ = *(const double2*)((EP)+2); \
  u0 += e01_.x*(A3); u1 += e01_.x*(B0); u2 += e01_.x*(B1); u3 += e01_.x*(B2); \
  u4 += e01_.x*(B3); u5 += e01_.x*(C0); u6 += e01_.x*(C1); u7 += e01_.x*(C2); \
  u0 += e01_.y*(A2); u1 += e01_.y*(A3); u2 += e01_.y*(B0); u3 += e01_.y*(B1); \
  u4 += e01_.y*(B2); u5 += e01_.y*(B3); u6 += e01_.y*(C0); u7 += e01_.y*(C1); \
  u0 += e23_.x*(A1); u1 += e23_.x*(A2); u2 += e23_.x*(A3); u3 += e23_.x*(B0); \
  u4 += e23_.x*(B1); u5 += e23_.x*(B2); u6 += e23_.x*(B3); u7 += e23_.x*(C0); \
  u0 += e23_.y*(A0); u1 += e23_.y*(A1); u2 += e23_.y*(A2); u3 += e23_.y*(A3); \
  u4 += e23_.y*(B0); u5 += e23_.y*(B1); u6 += e23_.y*(B2); u7 += e23_.y*(B3); }

#define LOADD(X0,X1,X2,X3, P) { \
  const double2 la_ = *(const double2*)(P); \
  const double2 lb_ = *(const double2*)((P)+2); \
  X0 = la_.x; X1 = la_.y; X2 = lb_.x; X3 = lb_.y; }

#define LOADF(X0,X1,X2,X3, P) { \
  const float4 lf_ = *(const float4*)(P); \
  X0 = (double)lf_.x; X1 = (double)lf_.y; X2 = (double)lf_.z; X3 = (double)lf_.w; }

__device__ __forceinline__ void init_eps_d(double* eps_d, int tid) {
  if (tid < 100) {
    float a = (float)tid / 10.0f;           // identical fp32 ops to reference
    float e = a * expf(1.0f - a);
    eps_d[tid] = (double)e;                 // exact widening
  }
}

// -------- mm1: z1[b,h,t] = sum_i W1[h,i] * x[b,i,t]  (proven clean) --------
// grid = 256 b * 4 t-chunks of 256; block 256 = 8 h-pairs x 32 t-octets
__global__ __launch_bounds__(256) void mm1(
    const float* __restrict__ x, const float* __restrict__ W1,
    float* __restrict__ z1)
{
  __shared__ double xe[13 * 128];
  __shared__ double xo[13 * 128];
  __shared__ double wd[16 * 80];

  const int tid = threadIdx.x;
  const int b   = blockIdx.x >> 2;
  const int tc  = blockIdx.x & 3;
  const int tcb = tc * 256;

  for (int idx = tid; idx < HID_ * IN_; idx += 256)
    wd[(idx / IN_) * 80 + (idx % IN_)] = (double)W1[idx];

  const int c    = tid;
  const int slot = ((c >> 3) << 2) | (c & 3);
  double* dst = (((c >> 2) & 1) ? xo : xe) + slot;
  const int t_c  = tcb + c;
  const bool cok = (t_c < T_);

  const int p = tid >> 5;
  const int q = tid & 31;

  double m00=0,m01=0,m02=0,m03=0,m04=0,m05=0,m06=0,m07=0;
  double m10=0,m11=0,m12=0,m13=0,m14=0,m15=0,m16=0,m17=0;

  for (int ci = 0; ci < 6; ++ci) {
    __syncthreads();
    {
      const float* xp = x + ((size_t)b * IN_ + ci * 13) * T_ + t_c;
#pragma unroll
      for (int r = 0; r < 13; ++r)
        dst[r * 128] = cok ? (double)xp[r * T_] : 0.0;
    }
    __syncthreads();
#pragma unroll
    for (int i = 0; i < 13; ++i) {
      double d0,d1,d2,d3,d4,d5,d6,d7;
      LOADD(d0,d1,d2,d3, &xe[i * 128 + 4 * q]);
      LOADD(d4,d5,d6,d7, &xo[i * 128 + 4 * q]);
      const double w0 = wd[(2*p)     * 80 + ci * 13 + i];
      const double w1 = wd[(2*p + 1) * 80 + ci * 13 + i];
      m00 += w0*d0; m01 += w0*d1; m02 += w0*d2; m03 += w0*d3;
      m04 += w0*d4; m05 += w0*d5; m06 += w0*d6; m07 += w0*d7;
      m10 += w1*d0; m11 += w1*d1; m12 += w1*d2; m13 += w1*d3;
      m14 += w1*d4; m15 += w1*d5; m16 += w1*d6; m17 += w1*d7;
    }
  }

  const int t8 = tcb + 8 * q;
  if (t8 + 7 < T_) {
    float* o0 = &z1[((size_t)b * HID_ + 2*p) * T_ + t8];
    float* o1 = &z1[((size_t)b * HID_ + 2*p + 1) * T_ + t8];
    *(float4*)(o0)     = make_float4((float)m00,(float)m01,(float)m02,(float)m03);
    *(float4*)(o0 + 4) = make_float4((float)m04,(float)m05,(float)m06,(float)m07);
    *(float4*)(o1)     = make_float4((float)m10,(float)m11,(float)m12,(float)m13);
    *(float4*)(o1 + 4) = make_float4((float)m14,(float)m15,(float)m16,(float)m17);
  }
}

// -------- mm2: z2[b,o,t] = sum_h W2[o,h] * s1[b,h,t] -----------------------
__global__ __launch_bounds__(256) void mm2(
    const float* __restrict__ s1, const float* __restrict__ W2,
    float* __restrict__ z2)
{
  __shared__ double se[16 * 128];
  __shared__ double so[16 * 128];
  __shared__ double wd[OUT_ * HID_];

  const int tid = threadIdx.x;
  const int b   = blockIdx.x >> 2;
  const int tc  = blockIdx.x & 3;
  const int tcb = tc * 256;

  for (int idx = tid; idx < OUT_ * HID_; idx += 256)   // 320 > 256: strided
    wd[idx] = (double)W2[idx];

  const int c    = tid;
  const int slot = ((c >> 3) << 2) | (c & 3);
  double* dst = (((c >> 2) & 1) ? so : se) + slot;
  const int t_c  = tcb + c;
  const bool cok = (t_c < T_);
  {
    const float* sp = s1 + (size_t)b * HID_ * T_ + t_c;
#pragma unroll
    for (int r = 0; r < HID_; ++r)
      dst[r * 128] = cok ? (double)sp[r * T_] : 0.0;
  }
  __syncthreads();

  const int p  = tid >> 5;
  const int q  = tid & 31;
  const int t8 = tcb + 8 * q;

  for (int pg = p; pg < 10; pg += 8) {
    double m00=0,m01=0,m02=0,m03=0,m04=0,m05=0,m06=0,m07=0;
    double m10=0,m11=0,m12=0,m13=0,m14=0,m15=0,m16=0,m17=0;
#pragma unroll
    for (int i = 0; i < HID_; ++i) {
      double d0,d1,d2,d3,d4,d5,d6,d7;
      LOADD(d0,d1,d2,d3, &se[i * 128 + 4 * q]);
      LOADD(d4,d5,d6,d7, &so[i * 128 + 4 * q]);
      const double w0 = wd[(2*pg)     * HID_ + i];
      const double w1 = wd[(2*pg + 1) * HID_ + i];
      m00 += w0*d0; m01 += w0*d1; m02 += w0*d2; m03 += w0*d3;
      m04 += w0*d4; m05 += w0*d5; m06 += w0*d6; m07 += w0*d7;
      m10 += w1*d0; m11 += w1*d1; m12 += w1*d2; m13 += w1*d3;
      m14 += w1*d4; m15 += w1*d5; m16 += w1*d6; m17 += w1*d7;
    }
    if (t8 + 7 < T_) {
      float* o0 = &z2[((size_t)b * OUT_ + 2*pg) * T_ + t8];
      float* o1 = &z2[((size_t)b * OUT_ + 2*pg + 1) * T_ + t8];
      *(float4*)(o0)     = make_float4((float)m00,(float)m01,(float)m02,(float)m03);
      *(float4*)(o0 + 4) = make_float4((float)m04,(float)m05,(float)m06,(float)m07);
      *(float4*)(o1)     = make_float4((float)m10,(float)m11,(float)m12,(float)m13);
      *(float4*)(o1 + 4) = make_float4((float)m14,(float)m15,(float)m16,(float)m17);
    }
  }
}

// -------- fir_g: sout = spike(FIR(zin)), R rows (16 or 20) -----------------
// z staged in LDS as fp32 (bit-identical: widened to double at reg load).
// FIR: group 0 unrolled, then 8 rolled iterations of 3 groups (period-3
// register rotation restores A/B/C naming each iteration).
// tile_fixed < 0: grid = B*8; else grid = B, single tile (in-place safe when
// tiles launched in DESCENDING order; tile k reads t < 125(k+1)).
__global__ __launch_bounds__(256) void fir_g(
    const float* __restrict__ zin, float* __restrict__ sout,
    int R, int tile_fixed)
{
  __shared__ float zf[OUT_ * ZSTR_];   // 18,240 B (R<=20)
  __shared__ __align__(16) double eps_d[100];

  const int tid  = threadIdx.x;
  const int b    = (tile_fixed >= 0) ? (int)blockIdx.x : (int)(blockIdx.x >> 3);
  const int tile = (tile_fixed >= 0) ? tile_fixed      : (int)(blockIdx.x & 7);
  const int t0   = tile * TT_;

  init_eps_d(eps_d, tid);
  for (int idx = tid; idx < R * ZSTR_; idx += 256) {
    const int cc = idx % ZSTR_;
    const int t  = t0 - 99 + cc;
    const int r  = idx / ZSTR_;
    zf[idx] = (cc < J_ && t >= 0) ? zin[((size_t)b * R + r) * T_ + t] : 0.0f;
  }
  __syncthreads();

  for (int task = tid; task < R * 16; task += 256) {
    const int h = task >> 4, q = task & 15;
    const float* zrow = &zf[h * ZSTR_ + 8 * q];
    double u0=0,u1=0,u2=0,u3=0,u4=0,u5=0,u6=0,u7=0;
    double A0,A1,A2,A3,B0,B1,B2,B3,C0,C1,C2,C3;
    LOADF(A0,A1,A2,A3, zrow + 96);               // quad 24
    LOADF(B0,B1,B2,B3, zrow + 100);              // quad 25
    LOADF(C0,C1,C2,C3, zrow + 104);              // quad 26
    GRP(eps_d, A0,A1,A2,A3, B0,B1,B2,B3, C0,C1,C2)   // group 0

    const float*  zp = zrow + 92;                // quad 23 (group 1's new quad)
    const double* ep = eps_d + 4;                // eps for group 1
#pragma unroll 1
    for (int k = 0; k < 8; ++k) {                // groups 3k+1 .. 3k+3
      LOADF(C0,C1,C2,C3, zp);
      GRP(ep,     C0,C1,C2,C3, A0,A1,A2,A3, B0,B1,B2)
      LOADF(B0,B1,B2,B3, zp - 4);
      GRP(ep + 4, B0,B1,B2,B3, C0,C1,C2,C3, A0,A1,A2)
      LOADF(A0,A1,A2,A3, zp - 8);
      GRP(ep + 8, A0,A1,A2,A3, B0,B1,B2,B3, C0,C1,C2)
      zp -= 12; ep += 12;
    }

    const size_t base = ((size_t)b * R + h) * T_ + t0 + 8 * q;
    const int tb = 8 * q;
    const float f0=(float)u0, f1=(float)u1, f2=(float)u2, f3=(float)u3;
    const float f4=(float)u4, f5=(float)u5, f6=(float)u6, f7=(float)u7;
    sout[base + 0] = (f0 >= 1.0f) ? 1.0f : 0.0f;   // tb+3 <= 123 always valid
    sout[base + 1] = (f1 >= 1.0f) ? 1.0f : 0.0f;
    sout[base + 2] = (f2 >= 1.0f) ? 1.0f : 0.0f;
    sout[base + 3] = (f3 >= 1.0f) ? 1.0f : 0.0f;
    if (tb + 4 < TT_) sout[base + 4] = (f4 >= 1.0f) ? 1.0f : 0.0f;
    if (tb + 5 < TT_) sout[base + 5] = (f5 >= 1.0f) ? 1.0f : 0.0f;
    if (tb + 6 < TT_) sout[base + 6] = (f6 >= 1.0f) ? 1.0f : 0.0f;
    if (tb + 7 < TT_) sout[base + 7] = (f7 >= 1.0f) ? 1.0f : 0.0f;
  }
}

extern "C" void kernel_launch(void* const* d_in, const int* in_sizes, int n_in,
                              void* d_out, int out_size, void* d_ws, size_t ws_size,
                              hipStream_t stream) {
  const float* x  = (const float*)d_in[0];
  const float* W1 = (const float*)d_in[1];
  const float* W2 = (const float*)d_in[2];
  float* outp = (float*)d_out;
  float* base = (float*)d_ws;

  const size_t Z1E = (size_t)B_ * HID_ * T_;   // 4.096M floats (16.4 MB)
  const size_t Z2E = (size_t)B_ * OUT_ * T_;   // 5.120M floats (20.5 MB)

  if (ws_size >= (Z1E + Z2E) * sizeof(float)) {
    float* z1 = base;
    float* s1 = base + Z2E;
    float* z2 = base;                            // reuses z1 space
    mm1<<<dim3(B_ * 4), dim3(256), 0, stream>>>(x, W1, z1);
    fir_g<<<dim3(B_ * 8), dim3(256), 0, stream>>>(z1, s1, HID_, -1);
    mm2<<<dim3(B_ * 4), dim3(256), 0, stream>>>(s1, W2, z2);
    fir_g<<<dim3(B_ * 8), dim3(256), 0, stream>>>(z2, outp, OUT_, -1);
  } else if (ws_size >= 2 * Z1E * sizeof(float)) {
    float* z1 = base;
    float* s1 = base + Z1E;
    mm1<<<dim3(B_ * 4), dim3(256), 0, stream>>>(x, W1, z1);
    fir_g<<<dim3(B_ * 8), dim3(256), 0, stream>>>(z1, s1, HID_, -1);
    mm2<<<dim3(B_ * 4), dim3(256), 0, stream>>>(s1, W2, outp);
    for (int k = 7; k >= 0; --k)
      fir_g<<<dim3(B_), dim3(256), 0, stream>>>(outp, outp, OUT_, k);
  } else {
    float* z1 = base;
    mm1<<<dim3(B_ * 4), dim3(256), 0, stream>>>(x, W1, z1);
    for (int k = 7; k >= 0; --k)
      fir_g<<<dim3(B_), dim3(256), 0, stream>>>(z1, z1, HID_, k);
    mm2<<<dim3(B_ * 4), dim3(256), 0, stream>>>(z1, W2, outp);
    for (int k = 7; k >= 0; --k)
      fir_g<<<dim3(B_), dim3(256), 0, stream>>>(outp, outp, OUT_, k);
  }
}

// Round 8
// 122.595 us; speedup vs baseline: 24.1650x; 1.1029x over previous
//
#include <hip/hip_runtime.h>
#include <math.h>

// SLAYER MLP forward: spike(psp(W2 @ spike(psp(W1 @ x))))
// B=256, IN=78, HID=16, OUT=20, T=1000, K=100 (SRM alpha, tau=10)
//
// fp64 accumulation everywhere (absmax 0.0 rounds 0-7), fp32 rounding at
// reference materialization points (einsum outputs z1/z2, final u).
//
// Round-8: mm1/mm2 rebuilt on the fir_g recipe (0 measured conflicts):
//  - activations staged in LDS as fp32 (x,s1 are exact {0,1}; widened to
//    double at register load -> bit-identical products)
//  - thread owns 4 (even,odd) t-pairs at stride 64: float2 LDS reads at
//    dword 4i+2q+64e -> 32 even-dword addrs, 2 lanes/bank = conflict-free
//  - float2 coalesced z-stores
// fir_g (rolled period-3 FIR) unchanged from round 7.

#define B_     256
#define IN_    78
#define HID_   16
#define OUT_   20
#define T_     1000
#define TT_    125
#define J_     224              // TT + K - 1
#define ZSTR_  228              // fir LDS row stride (floats)
#define XSTR_  260              // mm LDS row stride (floats)

// ---------------- FIR building blocks (named scalars only) ----------------
#define GRP(EP, A0,A1,A2,A3, B0,B1,B2,B3, C0,C1,C2) { \
  const double2 e01_ = *(const double2*)(EP); \
  const double2 e23_ = *(const double2*)((EP)+2); \
  u0 += e01_.x*(A3); u1 += e01_.x*(B0); u2 += e01_.x*(B1); u3 += e01_.x*(B2); \
  u4 += e01_.x*(B3); u5 += e01_.x*(C0); u6 += e01_.x*(C1); u7 += e01_.x*(C2); \
  u0 += e01_.y*(A2); u1 += e01_.y*(A3); u2 += e01_.y*(B0); u3 += e01_.y*(B1); \
  u4 += e01_.y*(B2); u5 += e01_.y*(B3); u6 += e01_.y*(C0); u7 += e01_.y*(C1); \
  u0 += e23_.x*(A1); u1 += e23_.x*(A2); u2 += e23_.x*(A3); u3 += e23_.x*(B0); \
  u4 += e23_.x*(B1); u5 += e23_.x*(B2); u6 += e23_.x*(B3); u7 += e23_.x*(C0); \
  u0 += e23_.y*(A0); u1 += e23_.y*(A1); u2 += e23_.y*(A2); u3 += e23_.y*(A3); \
  u4 += e23_.y*(B0); u5 += e23_.y*(B1); u6 += e23_.y*(B2); u7 += e23_.y*(B3); }

#define LOADF(X0,X1,X2,X3, P) { \
  const float4 lf_ = *(const float4*)(P); \
  X0 = (double)lf_.x; X1 = (double)lf_.y; X2 = (double)lf_.z; X3 = (double)lf_.w; }

__device__ __forceinline__ void init_eps_d(double* eps_d, int tid) {
  if (tid < 100) {
    float a = (float)tid / 10.0f;           // identical fp32 ops to reference
    float e = a * expf(1.0f - a);
    eps_d[tid] = (double)e;                 // exact widening
  }
}

// ---------------- mm building blocks --------------------------------------
// Per i-row: 4 float2 reads (t-pairs at stride 64) + 16 named-scalar dFMA.
#define MMROW(XR, W0, W1) { \
  const float2 f0_ = *(const float2*)((XR)); \
  const float2 f1_ = *(const float2*)((XR) + 64); \
  const float2 f2_ = *(const float2*)((XR) + 128); \
  const float2 f3_ = *(const float2*)((XR) + 192); \
  const double x0_=(double)f0_.x, x1_=(double)f0_.y; \
  const double x2_=(double)f1_.x, x3_=(double)f1_.y; \
  const double x4_=(double)f2_.x, x5_=(double)f2_.y; \
  const double x6_=(double)f3_.x, x7_=(double)f3_.y; \
  m00 += (W0)*x0_; m01 += (W0)*x1_; m02 += (W0)*x2_; m03 += (W0)*x3_; \
  m04 += (W0)*x4_; m05 += (W0)*x5_; m06 += (W0)*x6_; m07 += (W0)*x7_; \
  m10 += (W1)*x0_; m11 += (W1)*x1_; m12 += (W1)*x2_; m13 += (W1)*x3_; \
  m14 += (W1)*x4_; m15 += (W1)*x5_; m16 += (W1)*x6_; m17 += (W1)*x7_; }

// guarded coalesced float2 store of one accumulator pair (t even, t+1 odd)
#define STORE2(BASE, EOFF, MA, MB) \
  if (tb + (EOFF) < T_ - 1) \
    *(float2*)&zout[(BASE) + (size_t)(tb + (EOFF))] = \
        make_float2((float)(MA), (float)(MB));

// -------- mm1: z1[b,h,t] = sum_i W1[h,i] * x[b,i,t] ------------------------
// grid = 256 b * 4 t-chunks of 256; block 256 = 8 h-pairs x 32 lanes;
// lane q owns t-pairs {2q+64e, 2q+1+64e}, e = 0..3.
__global__ __launch_bounds__(256) void mm1(
    const float* __restrict__ x, const float* __restrict__ W1,
    float* __restrict__ zout)
{
  __shared__ float  xs[13 * XSTR_];   // 13,520 B
  __shared__ double wd[16 * 80];      // 10,240 B

  const int tid = threadIdx.x;
  const int b   = blockIdx.x >> 2;
  const int tc  = blockIdx.x & 3;
  const int tcb = tc * 256;

  for (int idx = tid; idx < HID_ * IN_; idx += 256)
    wd[(idx / IN_) * 80 + (idx % IN_)] = (double)W1[idx];

  const int  t_c = tcb + tid;
  const bool cok = (t_c < T_);
  const int p = tid >> 5;
  const int q = tid & 31;

  double m00=0,m01=0,m02=0,m03=0,m04=0,m05=0,m06=0,m07=0;
  double m10=0,m11=0,m12=0,m13=0,m14=0,m15=0,m16=0,m17=0;

  for (int ci = 0; ci < 6; ++ci) {
    __syncthreads();
    {
      const float* xp = x + ((size_t)b * IN_ + ci * 13) * T_ + t_c;
#pragma unroll
      for (int r = 0; r < 13; ++r)
        xs[r * XSTR_ + tid] = cok ? xp[r * T_] : 0.0f;
    }
    __syncthreads();
    const int wbase0 = (2*p)     * 80 + ci * 13;
    const int wbase1 = (2*p + 1) * 80 + ci * 13;
#pragma unroll
    for (int i = 0; i < 13; ++i) {
      const float* xr = &xs[i * XSTR_ + 2 * q];
      const double w0 = wd[wbase0 + i];
      const double w1 = wd[wbase1 + i];
      MMROW(xr, w0, w1)
    }
  }

  const size_t r0 = ((size_t)b * HID_ + 2*p) * T_;
  const size_t r1 = r0 + T_;
  const int tb = tcb + 2 * q;
  STORE2(r0,   0, m00, m01)  STORE2(r0,  64, m02, m03)
  STORE2(r0, 128, m04, m05)  STORE2(r0, 192, m06, m07)
  STORE2(r1,   0, m10, m11)  STORE2(r1,  64, m12, m13)
  STORE2(r1, 128, m14, m15)  STORE2(r1, 192, m16, m17)
}

// -------- mm2: z2[b,o,t] = sum_h W2[o,h] * s1[b,h,t] -----------------------
// Same lane layout; pg-loop covers 10 o-pairs with 8 p-slots.
__global__ __launch_bounds__(256) void mm2(
    const float* __restrict__ s1, const float* __restrict__ W2,
    float* __restrict__ zout)
{
  __shared__ float  ss[16 * XSTR_];   // 16,640 B
  __shared__ double wd[OUT_ * HID_];  //  2,560 B

  const int tid = threadIdx.x;
  const int b   = blockIdx.x >> 2;
  const int tc  = blockIdx.x & 3;
  const int tcb = tc * 256;

  for (int idx = tid; idx < OUT_ * HID_; idx += 256)   // 320 > 256: strided
    wd[idx] = (double)W2[idx];

  const int  t_c = tcb + tid;
  const bool cok = (t_c < T_);
  {
    const float* sp = s1 + (size_t)b * HID_ * T_ + t_c;
#pragma unroll
    for (int r = 0; r < HID_; ++r)
      ss[r * XSTR_ + tid] = cok ? sp[r * T_] : 0.0f;
  }
  __syncthreads();

  const int p = tid >> 5;
  const int q = tid & 31;
  const int tb = tcb + 2 * q;

  for (int pg = p; pg < 10; pg += 8) {
    double m00=0,m01=0,m02=0,m03=0,m04=0,m05=0,m06=0,m07=0;
    double m10=0,m11=0,m12=0,m13=0,m14=0,m15=0,m16=0,m17=0;
    const int wbase0 = (2*pg)     * HID_;
    const int wbase1 = (2*pg + 1) * HID_;
#pragma unroll
    for (int i = 0; i < HID_; ++i) {
      const float* xr = &ss[i * XSTR_ + 2 * q];
      const double w0 = wd[wbase0 + i];
      const double w1 = wd[wbase1 + i];
      MMROW(xr, w0, w1)
    }
    const size_t r0 = ((size_t)b * OUT_ + 2*pg) * T_;
    const size_t r1 = r0 + T_;
    STORE2(r0,   0, m00, m01)  STORE2(r0,  64, m02, m03)
    STORE2(r0, 128, m04, m05)  STORE2(r0, 192, m06, m07)
    STORE2(r1,   0, m10, m11)  STORE2(r1,  64, m12, m13)
    STORE2(r1, 128, m14, m15)  STORE2(r1, 192, m16, m17)
  }
}

// -------- fir_g: sout = spike(FIR(zin)), R rows (16 or 20) -----------------
// (unchanged from round 7: fp32 LDS staging, rolled period-3 FIR)
__global__ __launch_bounds__(256) void fir_g(
    const float* __restrict__ zin, float* __restrict__ sout,
    int R, int tile_fixed)
{
  __shared__ float zf[OUT_ * ZSTR_];   // 18,240 B (R<=20)
  __shared__ __align__(16) double eps_d[100];

  const int tid  = threadIdx.x;
  const int b    = (tile_fixed >= 0) ? (int)blockIdx.x : (int)(blockIdx.x >> 3);
  const int tile = (tile_fixed >= 0) ? tile_fixed      : (int)(blockIdx.x & 7);
  const int t0   = tile * TT_;

  init_eps_d(eps_d, tid);
  for (int idx = tid; idx < R * ZSTR_; idx += 256) {
    const int cc = idx % ZSTR_;
    const int t  = t0 - 99 + cc;
    const int r  = idx / ZSTR_;
    zf[idx] = (cc < J_ && t >= 0) ? zin[((size_t)b * R + r) * T_ + t] : 0.0f;
  }
  __syncthreads();

  for (int task = tid; task < R * 16; task += 256) {
    const int h = task >> 4, q = task & 15;
    const float* zrow = &zf[h * ZSTR_ + 8 * q];
    double u0=0,u1=0,u2=0,u3=0,u4=0,u5=0,u6=0,u7=0;
    double A0,A1,A2,A3,B0,B1,B2,B3,C0,C1,C2,C3;
    LOADF(A0,A1,A2,A3, zrow + 96);               // quad 24
    LOADF(B0,B1,B2,B3, zrow + 100);              // quad 25
    LOADF(C0,C1,C2,C3, zrow + 104);              // quad 26
    GRP(eps_d, A0,A1,A2,A3, B0,B1,B2,B3, C0,C1,C2)   // group 0

    const float*  zp = zrow + 92;                // quad 23 (group 1's new quad)
    const double* ep = eps_d + 4;                // eps for group 1
#pragma unroll 1
    for (int k = 0; k < 8; ++k) {                // groups 3k+1 .. 3k+3
      LOADF(C0,C1,C2,C3, zp);
      GRP(ep,     C0,C1,C2,C3, A0,A1,A2,A3, B0,B1,B2)
      LOADF(B0,B1,B2,B3, zp - 4);
      GRP(ep + 4, B0,B1,B2,B3, C0,C1,C2,C3, A0,A1,A2)
      LOADF(A0,A1,A2,A3, zp - 8);
      GRP(ep + 8, A0,A1,A2,A3, B0,B1,B2,B3, C0,C1,C2)
      zp -= 12; ep += 12;
    }

    const size_t base = ((size_t)b * R + h) * T_ + t0 + 8 * q;
    const int tb = 8 * q;
    const float f0=(float)u0, f1=(float)u1, f2=(float)u2, f3=(float)u3;
    const float f4=(float)u4, f5=(float)u5, f6=(float)u6, f7=(float)u7;
    sout[base + 0] = (f0 >= 1.0f) ? 1.0f : 0.0f;   // tb+3 <= 123 always valid
    sout[base + 1] = (f1 >= 1.0f) ? 1.0f : 0.0f;
    sout[base + 2] = (f2 >= 1.0f) ? 1.0f : 0.0f;
    sout[base + 3] = (f3 >= 1.0f) ? 1.0f : 0.0f;
    if (tb + 4 < TT_) sout[base + 4] = (f4 >= 1.0f) ? 1.0f : 0.0f;
    if (tb + 5 < TT_) sout[base + 5] = (f5 >= 1.0f) ? 1.0f : 0.0f;
    if (tb + 6 < TT_) sout[base + 6] = (f6 >= 1.0f) ? 1.0f : 0.0f;
    if (tb + 7 < TT_) sout[base + 7] = (f7 >= 1.0f) ? 1.0f : 0.0f;
  }
}

extern "C" void kernel_launch(void* const* d_in, const int* in_sizes, int n_in,
                              void* d_out, int out_size, void* d_ws, size_t ws_size,
                              hipStream_t stream) {
  const float* x  = (const float*)d_in[0];
  const float* W1 = (const float*)d_in[1];
  const float* W2 = (const float*)d_in[2];
  float* outp = (float*)d_out;
  float* base = (float*)d_ws;

  const size_t Z1E = (size_t)B_ * HID_ * T_;   // 4.096M floats (16.4 MB)
  const size_t Z2E = (size_t)B_ * OUT_ * T_;   // 5.120M floats (20.5 MB)

  if (ws_size >= (Z1E + Z2E) * sizeof(float)) {
    float* z1 = base;
    float* s1 = base + Z2E;
    float* z2 = base;                            // reuses z1 space
    mm1<<<dim3(B_ * 4), dim3(256), 0, stream>>>(x, W1, z1);
    fir_g<<<dim3(B_ * 8), dim3(256), 0, stream>>>(z1, s1, HID_, -1);
    mm2<<<dim3(B_ * 4), dim3(256), 0, stream>>>(s1, W2, z2);
    fir_g<<<dim3(B_ * 8), dim3(256), 0, stream>>>(z2, outp, OUT_, -1);
  } else if (ws_size >= 2 * Z1E * sizeof(float)) {
    float* z1 = base;
    float* s1 = base + Z1E;
    mm1<<<dim3(B_ * 4), dim3(256), 0, stream>>>(x, W1, z1);
    fir_g<<<dim3(B_ * 8), dim3(256), 0, stream>>>(z1, s1, HID_, -1);
    mm2<<<dim3(B_ * 4), dim3(256), 0, stream>>>(s1, W2, outp);
    for (int k = 7; k >= 0; --k)
      fir_g<<<dim3(B_), dim3(256), 0, stream>>>(outp, outp, OUT_, k);
  } else {
    float* z1 = base;
    mm1<<<dim3(B_ * 4), dim3(256), 0, stream>>>(x, W1, z1);
    for (int k = 7; k >= 0; --k)
      fir_g<<<dim3(B_), dim3(256), 0, stream>>>(z1, z1, HID_, k);
    mm2<<<dim3(B_ * 4), dim3(256), 0, stream>>>(z1, W2, outp);
    for (int k = 7; k >= 0; --k)
      fir_g<<<dim3(B_), dim3(256), 0, stream>>>(outp, outp, OUT_, k);
  }
}

// Round 9
// 109.771 us; speedup vs baseline: 26.9879x; 1.1168x over previous
//
#include <hip/hip_runtime.h>
#include <math.h>

// SLAYER MLP forward: spike(psp(W2 @ spike(psp(W1 @ x))))
// B=256, IN=78, HID=16, OUT=20, T=1000, K=100 (SRM alpha, tau=10)
//
// fp64 accumulation everywhere (absmax 0.0 rounds 0-8), fp32 rounding at
// reference materialization points (einsum outputs z1/z2, final u).
//
// Round-9: mm1/mm2 latency-hiding rebuild (round 8 measured mm1 at 28%
// VALUBusy, 36% occupancy = grid-limited TLP + exposed staging latency):
//  - t-chunks of 128 -> grid 2048 = 8 blocks/CU (LDS ~7-9 KB, 8 acc/thread)
//  - mm1: T14 issue-early/write-late: next chunk's x in 7 named regs, loads
//    issued BEFORE computing current chunk, written to LDS after barrier
//  - same proven conflict-free float2 lane layout (14K conflicts in round 8)
// fir_g (rolled period-3 FIR) unchanged.

#define B_     256
#define IN_    78
#define HID_   16
#define OUT_   20
#define T_     1000
#define TT_    125
#define J_     224              // TT + K - 1
#define ZSTR_  228              // fir LDS row stride (floats)
#define TC_    128              // mm t-chunk
#define MSTR_  132              // mm LDS row stride (floats)

// ---------------- FIR building blocks (named scalars only) ----------------
#define GRP(EP, A0,A1,A2,A3, B0,B1,B2,B3, C0,C1,C2) { \
  const double2 e01_ = *(const double2*)(EP); \
  const double2 e23_ = *(const double2*)((EP)+2); \
  u0 += e01_.x*(A3); u1 += e01_.x*(B0); u2 += e01_.x*(B1); u3 += e01_.x*(B2); \
  u4 += e01_.x*(B3); u5 += e01_.x*(C0); u6 += e01_.x*(C1); u7 += e01_.x*(C2); \
  u0 += e01_.y*(A2); u1 += e01_.y*(A3); u2 += e01_.y*(B0); u3 += e01_.y*(B1); \
  u4 += e01_.y*(B2); u5 += e01_.y*(B3); u6 += e01_.y*(C0); u7 += e01_.y*(C1); \
  u0 += e23_.x*(A1); u1 += e23_.x*(A2); u2 += e23_.x*(A3); u3 += e23_.x*(B0); \
  u4 += e23_.x*(B1); u5 += e23_.x*(B2); u6 += e23_.x*(B3); u7 += e23_.x*(C0); \
  u0 += e23_.y*(A0); u1 += e23_.y*(A1); u2 += e23_.y*(A2); u3 += e23_.y*(A3); \
  u4 += e23_.y*(B0); u5 += e23_.y*(B1); u6 += e23_.y*(B2); u7 += e23_.y*(B3); }

#define LOADF(X0,X1,X2,X3, P) { \
  const float4 lf_ = *(const float4*)(P); \
  X0 = (double)lf_.x; X1 = (double)lf_.y; X2 = (double)lf_.z; X3 = (double)lf_.w; }

__device__ __forceinline__ void init_eps_d(double* eps_d, int tid) {
  if (tid < 100) {
    float a = (float)tid / 10.0f;           // identical fp32 ops to reference
    float e = a * expf(1.0f - a);
    eps_d[tid] = (double)e;                 // exact widening
  }
}

// ---------------- mm building blocks --------------------------------------
// Per i-row: 2 float2 reads (t-pairs at stride 64) + 8 named-scalar dFMA.
#define MMROW2(XR, W0, W1) { \
  const float2 f0_ = *(const float2*)(XR); \
  const float2 f1_ = *(const float2*)((XR) + 64); \
  const double x0_=(double)f0_.x, x1_=(double)f0_.y; \
  const double x2_=(double)f1_.x, x3_=(double)f1_.y; \
  m00 += (W0)*x0_; m01 += (W0)*x1_; m02 += (W0)*x2_; m03 += (W0)*x3_; \
  m10 += (W1)*x0_; m11 += (W1)*x1_; m12 += (W1)*x2_; m13 += (W1)*x3_; }

#define STORE2(BASE, EOFF, MA, MB) \
  if (tb + (EOFF) < T_ - 1) \
    *(float2*)&zout[(BASE) + (size_t)(tb + (EOFF))] = \
        make_float2((float)(MA), (float)(MB));

// -------- mm1: z1[b,h,t] = sum_i W1[h,i] * x[b,i,t] ------------------------
// grid = 256 b * 8 t-chunks of 128; block 256 = 8 h-pairs x 32 lanes.
// Lane q owns t-pairs {2q, 2q+1} and {2q+64, 2q+65} within the chunk.
// Staging: thread owns col c=tid&127, rows r0, r0+2, .., r0+12 (r0=tid>>7);
// 7 named regs double-buffer the next chunk (issue-early / write-late).
__global__ __launch_bounds__(256) void mm1(
    const float* __restrict__ x, const float* __restrict__ W1,
    float* __restrict__ zout)
{
  __shared__ float  xs[13 * MSTR_];   // 6,864 B
  __shared__ double wd[16 * 80];      // 10,240 B

  const int tid = threadIdx.x;
  const int b   = blockIdx.x >> 3;
  const int tc  = blockIdx.x & 7;
  const int tcb = tc * TC_;

  for (int idx = tid; idx < HID_ * IN_; idx += 256)
    wd[(idx / IN_) * 80 + (idx % IN_)] = (double)W1[idx];

  const int  c_  = tid & 127;
  const int  r0_ = tid >> 7;          // 0 or 1
  const int  tg_ = tcb + c_;
  const bool tok = (tg_ < T_);
  const bool t6  = tok && (r0_ == 0); // row 12 exists only for r0=0

  const int p = tid >> 5;
  const int q = tid & 31;

  double m00=0,m01=0,m02=0,m03=0,m10=0,m11=0,m12=0,m13=0;
  float g0,g1,g2,g3,g4,g5,g6;

#define ISSUE_MM1(CI) { \
    const float* xb_ = x + ((size_t)b * IN_ + (CI) * 13 + r0_) * T_ + tg_; \
    g0 = tok ? xb_[0]       : 0.0f; \
    g1 = tok ? xb_[2  * T_] : 0.0f; \
    g2 = tok ? xb_[4  * T_] : 0.0f; \
    g3 = tok ? xb_[6  * T_] : 0.0f; \
    g4 = tok ? xb_[8  * T_] : 0.0f; \
    g5 = tok ? xb_[10 * T_] : 0.0f; \
    g6 = t6  ? xb_[12 * T_] : 0.0f; }

  ISSUE_MM1(0)
  for (int ci = 0; ci < 6; ++ci) {
    __syncthreads();                  // previous chunk's reads complete
    {
      float* dst = &xs[r0_ * MSTR_ + c_];
      dst[0]          = g0;  dst[2  * MSTR_] = g1;
      dst[4  * MSTR_] = g2;  dst[6  * MSTR_] = g3;
      dst[8  * MSTR_] = g4;  dst[10 * MSTR_] = g5;
      if (r0_ == 0) dst[12 * MSTR_] = g6;
    }
    __syncthreads();
    if (ci < 5) ISSUE_MM1(ci + 1)     // loads fly under the compute below
    const int wbase0 = (2*p)     * 80 + ci * 13;
    const int wbase1 = (2*p + 1) * 80 + ci * 13;
#pragma unroll
    for (int i = 0; i < 13; ++i) {
      const float* xr = &xs[i * MSTR_ + 2 * q];
      MMROW2(xr, wd[wbase0 + i], wd[wbase1 + i])
    }
  }

  const size_t r0s = ((size_t)b * HID_ + 2*p) * T_;
  const size_t r1s = r0s + T_;
  const int tb = tcb + 2 * q;
  STORE2(r0s,  0, m00, m01)  STORE2(r0s, 64, m02, m03)
  STORE2(r1s,  0, m10, m11)  STORE2(r1s, 64, m12, m13)
}

// -------- mm2: z2[b,o,t] = sum_h W2[o,h] * s1[b,h,t] -----------------------
// grid = 256 b * 8 t-chunks of 128; one-shot staging (16 rows x 128 cols).
__global__ __launch_bounds__(256) void mm2(
    const float* __restrict__ s1, const float* __restrict__ W2,
    float* __restrict__ zout)
{
  __shared__ float  ss[16 * MSTR_];   // 8,448 B
  __shared__ double wd[OUT_ * HID_];  // 2,560 B

  const int tid = threadIdx.x;
  const int b   = blockIdx.x >> 3;
  const int tc  = blockIdx.x & 7;
  const int tcb = tc * TC_;

  for (int idx = tid; idx < OUT_ * HID_; idx += 256)   // 320 > 256: strided
    wd[idx] = (double)W2[idx];

  {
    const int  c_  = tid & 127;
    const int  r0_ = tid >> 7;
    const int  tg_ = tcb + c_;
    const bool tok = (tg_ < T_);
    const float* sb = s1 + ((size_t)b * HID_ + r0_) * T_ + tg_;
    float* dst = &ss[r0_ * MSTR_ + c_];
#pragma unroll
    for (int e = 0; e < 8; ++e)                        // rows r0_, r0_+2, ..
      dst[2 * e * MSTR_] = tok ? sb[2 * e * T_] : 0.0f;
  }
  __syncthreads();

  const int p  = tid >> 5;
  const int q  = tid & 31;
  const int tb = tcb + 2 * q;

  for (int pg = p; pg < 10; pg += 8) {
    double m00=0,m01=0,m02=0,m03=0,m10=0,m11=0,m12=0,m13=0;
    const int wbase0 = (2*pg)     * HID_;
    const int wbase1 = (2*pg + 1) * HID_;
#pragma unroll
    for (int i = 0; i < HID_; ++i) {
      const float* xr = &ss[i * MSTR_ + 2 * q];
      MMROW2(xr, wd[wbase0 + i], wd[wbase1 + i])
    }
    const size_t r0s = ((size_t)b * OUT_ + 2*pg) * T_;
    const size_t r1s = r0s + T_;
    STORE2(r0s,  0, m00, m01)  STORE2(r0s, 64, m02, m03)
    STORE2(r1s,  0, m10, m11)  STORE2(r1s, 64, m12, m13)
  }
}

// -------- fir_g: sout = spike(FIR(zin)), R rows (16 or 20) -----------------
// (unchanged from round 7: fp32 LDS staging, rolled period-3 FIR)
__global__ __launch_bounds__(256) void fir_g(
    const float* __restrict__ zin, float* __restrict__ sout,
    int R, int tile_fixed)
{
  __shared__ float zf[OUT_ * ZSTR_];   // 18,240 B (R<=20)
  __shared__ __align__(16) double eps_d[100];

  const int tid  = threadIdx.x;
  const int b    = (tile_fixed >= 0) ? (int)blockIdx.x : (int)(blockIdx.x >> 3);
  const int tile = (tile_fixed >= 0) ? tile_fixed      : (int)(blockIdx.x & 7);
  const int t0   = tile * TT_;

  init_eps_d(eps_d, tid);
  for (int idx = tid; idx < R * ZSTR_; idx += 256) {
    const int cc = idx % ZSTR_;
    const int t  = t0 - 99 + cc;
    const int r  = idx / ZSTR_;
    zf[idx] = (cc < J_ && t >= 0) ? zin[((size_t)b * R + r) * T_ + t] : 0.0f;
  }
  __syncthreads();

  for (int task = tid; task < R * 16; task += 256) {
    const int h = task >> 4, q = task & 15;
    const float* zrow = &zf[h * ZSTR_ + 8 * q];
    double u0=0,u1=0,u2=0,u3=0,u4=0,u5=0,u6=0,u7=0;
    double A0,A1,A2,A3,B0,B1,B2,B3,C0,C1,C2,C3;
    LOADF(A0,A1,A2,A3, zrow + 96);               // quad 24
    LOADF(B0,B1,B2,B3, zrow + 100);              // quad 25
    LOADF(C0,C1,C2,C3, zrow + 104);              // quad 26
    GRP(eps_d, A0,A1,A2,A3, B0,B1,B2,B3, C0,C1,C2)   // group 0

    const float*  zp = zrow + 92;                // quad 23 (group 1's new quad)
    const double* ep = eps_d + 4;                // eps for group 1
#pragma unroll 1
    for (int k = 0; k < 8; ++k) {                // groups 3k+1 .. 3k+3
      LOADF(C0,C1,C2,C3, zp);
      GRP(ep,     C0,C1,C2,C3, A0,A1,A2,A3, B0,B1,B2)
      LOADF(B0,B1,B2,B3, zp - 4);
      GRP(ep + 4, B0,B1,B2,B3, C0,C1,C2,C3, A0,A1,A2)
      LOADF(A0,A1,A2,A3, zp - 8);
      GRP(ep + 8, A0,A1,A2,A3, B0,B1,B2,B3, C0,C1,C2)
      zp -= 12; ep += 12;
    }

    const size_t base = ((size_t)b * R + h) * T_ + t0 + 8 * q;
    const int tb = 8 * q;
    const float f0=(float)u0, f1=(float)u1, f2=(float)u2, f3=(float)u3;
    const float f4=(float)u4, f5=(float)u5, f6=(float)u6, f7=(float)u7;
    sout[base + 0] = (f0 >= 1.0f) ? 1.0f : 0.0f;   // tb+3 <= 123 always valid
    sout[base + 1] = (f1 >= 1.0f) ? 1.0f : 0.0f;
    sout[base + 2] = (f2 >= 1.0f) ? 1.0f : 0.0f;
    sout[base + 3] = (f3 >= 1.0f) ? 1.0f : 0.0f;
    if (tb + 4 < TT_) sout[base + 4] = (f4 >= 1.0f) ? 1.0f : 0.0f;
    if (tb + 5 < TT_) sout[base + 5] = (f5 >= 1.0f) ? 1.0f : 0.0f;
    if (tb + 6 < TT_) sout[base + 6] = (f6 >= 1.0f) ? 1.0f : 0.0f;
    if (tb + 7 < TT_) sout[base + 7] = (f7 >= 1.0f) ? 1.0f : 0.0f;
  }
}

extern "C" void kernel_launch(void* const* d_in, const int* in_sizes, int n_in,
                              void* d_out, int out_size, void* d_ws, size_t ws_size,
                              hipStream_t stream) {
  const float* x  = (const float*)d_in[0];
  const float* W1 = (const float*)d_in[1];
  const float* W2 = (const float*)d_in[2];
  float* outp = (float*)d_out;
  float* base = (float*)d_ws;

  const size_t Z1E = (size_t)B_ * HID_ * T_;   // 4.096M floats (16.4 MB)
  const size_t Z2E = (size_t)B_ * OUT_ * T_;   // 5.120M floats (20.5 MB)

  if (ws_size >= (Z1E + Z2E) * sizeof(float)) {
    float* z1 = base;
    float* s1 = base + Z2E;
    float* z2 = base;                            // reuses z1 space
    mm1<<<dim3(B_ * 8), dim3(256), 0, stream>>>(x, W1, z1);
    fir_g<<<dim3(B_ * 8), dim3(256), 0, stream>>>(z1, s1, HID_, -1);
    mm2<<<dim3(B_ * 8), dim3(256), 0, stream>>>(s1, W2, z2);
    fir_g<<<dim3(B_ * 8), dim3(256), 0, stream>>>(z2, outp, OUT_, -1);
  } else if (ws_size >= 2 * Z1E * sizeof(float)) {
    float* z1 = base;
    float* s1 = base + Z1E;
    mm1<<<dim3(B_ * 8), dim3(256), 0, stream>>>(x, W1, z1);
    fir_g<<<dim3(B_ * 8), dim3(256), 0, stream>>>(z1, s1, HID_, -1);
    mm2<<<dim3(B_ * 8), dim3(256), 0, stream>>>(s1, W2, outp);
    for (int k = 7; k >= 0; --k)
      fir_g<<<dim3(B_), dim3(256), 0, stream>>>(outp, outp, OUT_, k);
  } else {
    float* z1 = base;
    mm1<<<dim3(B_ * 8), dim3(256), 0, stream>>>(x, W1, z1);
    for (int k = 7; k >= 0; --k)
      fir_g<<<dim3(B_), dim3(256), 0, stream>>>(z1, z1, HID_, k);
    mm2<<<dim3(B_ * 8), dim3(256), 0, stream>>>(z1, W2, outp);
    for (int k = 7; k >= 0; --k)
      fir_g<<<dim3(B_), dim3(256), 0, stream>>>(outp, outp, OUT_, k);
  }
}